// Round 2
// baseline (102.494 us; speedup 1.0000x reference)
//
#include <hip/hip_runtime.h>
#include <math.h>

// Problem constants
#define BB 8
#define HH 1024
#define TT 64                    // tile dim
#define NT (HH / TT)             // 16 tiles per axis
#define NOFF ((NT * (NT - 1)) / 2)   // 120 off-diagonal pairs
#define NPAIR (NOFF + NT)            // 136 pairs incl. diagonal
#define LDP 68                   // padded LDS row stride (17 float4; 68%32=4 -> mild-or-no conflicts)
#define C2PI 0.15915494309189535f    // 1/(2*pi): v_sin_f32 takes revolutions

// Symmetric-pair scheme: A_lat = relu(0.5(A+A^T)) is SYMMETRIC, so block (P,Q), P<=Q,
// reads tiles A[P,Q] and A[Q,P] ONCE each (A traffic 64MB -> 32MB), builds the lat tile
// (and its transpose) in LDS, then:
//   pass 1: contributions to rows in P   (sin(th_j - th_i - alpha[i,j]))
//   pass 2: contributions to rows in Q   (sin(th_i - th_j - alpha[j,i]))
// Partials land in ws[(b*NT + otherTile)*HH + i] (float4); ws poison fill is
// harness-unconditional (verified r1), so using ws costs nothing.

__device__ __forceinline__ void do_pass(
    const float* __restrict__ lat,      // LDS lat tile, row-major [TT][LDP] in (row,col) coords
    const float4* __restrict__ thRow,   // LDS theta*C2PI for the 64 output rows
    const float4* __restrict__ thCol,   // LDS theta*C2PI for the 64 summed cols
    const float* __restrict__ alpha,    // global alpha base
    int arow0, int acol0,               // alpha[arow0+r][acol0+c]
    float4* __restrict__ ws4,
    size_t wsSlotBase,                  // (b*NT + other)*HH + rowTileBase
    int tr, int tc)
{
    float acc[4][4];
    #pragma unroll
    for (int k = 0; k < 4; ++k)
        #pragma unroll
        for (int d = 0; d < 4; ++d) acc[k][d] = 0.f;

    // column thetas: c = 4*tc + m, independent of k
    float4 thq[4];
    #pragma unroll
    for (int m = 0; m < 4; ++m) thq[m] = thCol[4 * tc + m];

    #pragma unroll
    for (int k = 0; k < 4; ++k) {
        const int r = tr + 16 * k;
        const float4 thp  = thRow[r];
        const float4 lat4 = *(const float4*)&lat[r * LDP + 4 * tc];
        const float4 al4  = *(const float4*)&alpha[(size_t)(arow0 + r) * HH + acol0 + 4 * tc];
        #pragma unroll
        for (int m = 0; m < 4; ++m) {
            const float lm  = (&lat4.x)[m];
            const float alc = (&al4.x)[m] * C2PI;
            const float4 tq = thq[m];
            acc[k][0] += lm * __builtin_amdgcn_sinf(tq.x - thp.x - alc);
            acc[k][1] += lm * __builtin_amdgcn_sinf(tq.y - thp.y - alc);
            acc[k][2] += lm * __builtin_amdgcn_sinf(tq.z - thp.z - alc);
            acc[k][3] += lm * __builtin_amdgcn_sinf(tq.w - thp.w - alc);
        }
    }

    // reduce across the 16 tc lanes (lane-contiguous within a wave)
    #pragma unroll
    for (int off = 8; off >= 1; off >>= 1)
        #pragma unroll
        for (int k = 0; k < 4; ++k)
            #pragma unroll
            for (int d = 0; d < 4; ++d)
                acc[k][d] += __shfl_down(acc[k][d], off, 16);

    if (tc == 0) {
        #pragma unroll
        for (int k = 0; k < 4; ++k) {
            float4 r4;
            r4.x = acc[k][0]; r4.y = acc[k][1]; r4.z = acc[k][2]; r4.w = acc[k][3];
            ws4[wsSlotBase + tr + 16 * k] = r4;
        }
    }
}

__global__ __launch_bounds__(256, 4) void kuramoto_partial(
    const float* __restrict__ theta, const float* __restrict__ A,
    const float* __restrict__ alpha, float* __restrict__ ws)
{
    __shared__ float  sLat [TT * LDP];   // lat[r][c]  (r = P-local i, c = Q-local j)
    __shared__ float  sLatT[TT * LDP];   // lat[c][r]
    __shared__ float4 sThP[TT], sThQ[TT];

    const int blk = blockIdx.x;
    const int b   = blk / NPAIR;
    const int p   = blk - b * NPAIR;
    int P, Q;
    if (p < NOFF) {                      // unrank strict-upper-triangle pair
        int pp = p, row = 0;
        while (pp >= NT - 1 - row) { pp -= NT - 1 - row; ++row; }
        P = row; Q = row + 1 + pp;
    } else {
        P = Q = p - NOFF;
    }
    const bool diag = (P == Q);
    const int p0 = P * TT, q0 = Q * TT;

    const int t  = threadIdx.x;
    const int tr = t >> 4;               // 0..15
    const int tc = t & 15;               // 0..15
    const int rr = t >> 2;               // staging row 0..63
    const int cs = (t & 3) * 16;         // staging col base

    const float* Ab = A + (size_t)b * HH * HH;

    // ---- stage raw A tiles (coalesced 64B-per-row float4 reads) ----
    {
        const float* gA = Ab + (size_t)(p0 + rr) * HH + q0 + cs;   // A[P,Q] tile row
        float* dst = &sLat[rr * LDP + cs];
        #pragma unroll
        for (int q = 0; q < 4; ++q)
            *(float4*)&dst[4 * q] = *(const float4*)&gA[4 * q];
    }
    if (!diag) {
        const float* gB = Ab + (size_t)(q0 + rr) * HH + p0 + cs;   // A[Q,P] tile row
        float* dst = &sLatT[rr * LDP + cs];
        #pragma unroll
        for (int q = 0; q < 4; ++q)
            *(float4*)&dst[4 * q] = *(const float4*)&gB[4 * q];
    }
    // theta tiles, pre-scaled to revolutions
    if (t < TT) {
        float4 v = ((const float4*)theta)[(size_t)b * HH + p0 + t];
        v.x *= C2PI; v.y *= C2PI; v.z *= C2PI; v.w *= C2PI;
        sThP[t] = v;
    } else if (t < 2 * TT) {
        const int u = t - TT;
        float4 v = ((const float4*)theta)[(size_t)b * HH + q0 + u];
        v.x *= C2PI; v.y *= C2PI; v.z *= C2PI; v.w *= C2PI;
        sThQ[u] = v;
    }
    __syncthreads();

    // ---- symmetrize + relu in place ----
    if (!diag) {
        // each LDS word below is read+written by exactly ONE thread -> no extra barrier
        float lv[16];
        #pragma unroll
        for (int e = 0; e < 16; ++e) {
            const int c = cs + e;
            lv[e] = fmaxf(0.5f * (sLat[rr * LDP + c] + sLatT[c * LDP + rr]), 0.0f);
        }
        #pragma unroll
        for (int e = 0; e < 16; ++e) {
            const int c = cs + e;
            sLat [rr * LDP + c]  = lv[e];
            sLatT[c * LDP + rr]  = lv[e];
        }
    } else {
        // raw[c][r] is also read by the (c,r)-owner -> must barrier between read and write
        float lv[16];
        #pragma unroll
        for (int e = 0; e < 16; ++e) {
            const int c = cs + e;
            lv[e] = fmaxf(0.5f * (sLat[rr * LDP + c] + sLat[c * LDP + rr]), 0.0f);
        }
        __syncthreads();
        #pragma unroll
        for (int e = 0; e < 16; ++e)
            sLat[rr * LDP + cs + e] = lv[e];
    }
    __syncthreads();

    float4* ws4 = (float4*)ws;

    // pass 1: rows in P, cols in Q, slot=Q
    do_pass(sLat, sThP, sThQ, alpha, p0, q0, ws4,
            (size_t)(b * NT + Q) * HH + p0, tr, tc);

    // pass 2 (off-diag only): rows in Q, cols in P, slot=P
    if (!diag)
        do_pass(sLatT, sThQ, sThP, alpha, q0, p0, ws4,
                (size_t)(b * NT + P) * HH + q0, tr, tc);
}

__global__ __launch_bounds__(256) void kuramoto_final(
    const float* __restrict__ theta, const float* __restrict__ gamma,
    const float* __restrict__ omega, const float* __restrict__ kappa,
    const float* __restrict__ ws, float* __restrict__ out)
{
    const int idx = blockIdx.x * 256 + threadIdx.x;   // (b,i) flat, 8192 total
    const int i   = idx & (HH - 1);
    const int b   = idx >> 10;
    const float4* w4 = (const float4*)ws;

    float4 psum = w4[((size_t)b * NT) * HH + i];
    #pragma unroll
    for (int o = 1; o < NT; ++o) {
        const float4 q = w4[((size_t)b * NT + o) * HH + i];
        psum.x += q.x; psum.y += q.y; psum.z += q.z; psum.w += q.w;
    }

    const float4 th = ((const float4*)theta)[idx];
    const float4 om = ((const float4*)omega)[i];
    const float4 kp = ((const float4*)kappa)[i];
    const float  g  = gamma[idx];
    const float  inv = 1.0f / HH;   // K_COUP = 1, DT = 1

    float4 o;
    o.x = th.x + om.x + psum.x * inv + kp.x * (g - th.x);
    o.y = th.y + om.y + psum.y * inv + kp.y * (g - th.y);
    o.z = th.z + om.z + psum.z * inv + kp.z * (g - th.z);
    o.w = th.w + om.w + psum.w * inv + kp.w * (g - th.w);
    ((float4*)out)[idx] = o;
}

extern "C" void kernel_launch(void* const* d_in, const int* in_sizes, int n_in,
                              void* d_out, int out_size, void* d_ws, size_t ws_size,
                              hipStream_t stream) {
    const float* theta = (const float*)d_in[0];
    const float* gamma = (const float*)d_in[1];
    const float* A     = (const float*)d_in[2];
    const float* omega = (const float*)d_in[3];
    const float* kappa = (const float*)d_in[4];
    const float* alpha = (const float*)d_in[5];
    float* out = (float*)d_out;
    float* ws  = (float*)d_ws;

    hipLaunchKernelGGL(kuramoto_partial, dim3(BB * NPAIR), dim3(256), 0, stream,
                       theta, A, alpha, ws);
    hipLaunchKernelGGL(kuramoto_final, dim3(BB * HH / 256), dim3(256), 0, stream,
                       theta, gamma, omega, kappa, ws, out);
}

// Round 5
// 101.822 us; speedup vs baseline: 1.0066x; 1.0066x over previous
//
#include <hip/hip_runtime.h>
#include <math.h>

// Problem constants
#define BB 8
#define HH 1024
#define TT 64                    // tile dim
#define NT (HH / TT)             // 16 tiles per axis
#define NOFF ((NT * (NT - 1)) / 2)   // 120 off-diagonal pairs
#define NPAIR (NOFF + NT)            // 136 pairs incl. diagonal
#define LDP 68                   // padded LDS row stride
#define C2PI 0.15915494309189535f    // 1/(2*pi): v_sin_f32 takes revolutions

// Structure (identical to r4; r4's bench was an infra failure, not a kernel
// result — resubmitting unchanged):
// A_lat = relu(0.5(A+A^T)) is symmetric => block (P<=Q) reads tiles A[P,Q] and
// A[Q,P] ONCE each (A traffic 64MB -> 32MB, the only reducible HBM term).
// 512 threads: half 0 computes contributions to rows in P, half 1 to rows in Q,
// CONCURRENTLY (r2's serial version doubled the critical path and regressed).
// r3 bug: staging loaded only 4 floats/thread (16 of 64 tile columns) ->
// uninitialized LDS. Restored to 16 floats/thread as in the passing r2.

__device__ __forceinline__ void do_pass(
    const float* __restrict__ lat,      // LDS lat tile [row][LDP]
    const float4* __restrict__ thRow,   // theta*C2PI for the 64 output rows
    const float4* __restrict__ thCol,   // theta*C2PI for the 64 summed cols
    const float* __restrict__ alpha,    // global alpha base
    int arow0, int acol0,
    float4* __restrict__ ws4,
    size_t wsSlotBase,                  // (b*NT + other)*HH + rowTileBase
    int tr, int tc)
{
    float acc[4][4];
    #pragma unroll
    for (int k = 0; k < 4; ++k)
        #pragma unroll
        for (int d = 0; d < 4; ++d) acc[k][d] = 0.f;

    float4 thq[4];
    #pragma unroll
    for (int m = 0; m < 4; ++m) thq[m] = thCol[4 * tc + m];

    #pragma unroll
    for (int k = 0; k < 4; ++k) {
        const int r = tr + 16 * k;
        const float4 thp  = thRow[r];
        const float4 lat4 = *(const float4*)&lat[r * LDP + 4 * tc];
        const float4 al4  = *(const float4*)&alpha[(size_t)(arow0 + r) * HH + acol0 + 4 * tc];
        #pragma unroll
        for (int m = 0; m < 4; ++m) {
            const float lm  = (&lat4.x)[m];
            const float alc = (&al4.x)[m] * C2PI;
            const float4 tq = thq[m];
            acc[k][0] += lm * __builtin_amdgcn_sinf(tq.x - thp.x - alc);
            acc[k][1] += lm * __builtin_amdgcn_sinf(tq.y - thp.y - alc);
            acc[k][2] += lm * __builtin_amdgcn_sinf(tq.z - thp.z - alc);
            acc[k][3] += lm * __builtin_amdgcn_sinf(tq.w - thp.w - alc);
        }
    }

    // reduce across the 16 tc lanes (lane-contiguous in a wave)
    #pragma unroll
    for (int off = 8; off >= 1; off >>= 1)
        #pragma unroll
        for (int k = 0; k < 4; ++k)
            #pragma unroll
            for (int d = 0; d < 4; ++d)
                acc[k][d] += __shfl_down(acc[k][d], off, 16);

    if (tc == 0) {
        #pragma unroll
        for (int k = 0; k < 4; ++k) {
            float4 r4;
            r4.x = acc[k][0]; r4.y = acc[k][1]; r4.z = acc[k][2]; r4.w = acc[k][3];
            ws4[wsSlotBase + tr + 16 * k] = r4;
        }
    }
}

__global__ __launch_bounds__(512, 4) void kuramoto_partial(
    const float* __restrict__ theta, const float* __restrict__ A,
    const float* __restrict__ alpha, float* __restrict__ ws)
{
    __shared__ float  sLat [TT * LDP];   // lat[r][c]   (r = P-local, c = Q-local)
    __shared__ float  sLatT[TT * LDP];   // lat[c][r]
    __shared__ float4 sThP[TT], sThQ[TT];

    const int blk = blockIdx.x;
    const int b   = blk / NPAIR;
    const int p   = blk - b * NPAIR;
    int P, Q;
    if (p < NOFF) {                      // unrank strict-upper-triangle pair
        int pp = p, row = 0;
        while (pp >= NT - 1 - row) { pp -= NT - 1 - row; ++row; }
        P = row; Q = row + 1 + pp;
    } else {
        P = Q = p - NOFF;
    }
    const bool diag = (P == Q);
    const int p0 = P * TT, q0 = Q * TT;

    const int t    = threadIdx.x;
    const int half = t >> 8;             // 0: pass1 (rows P), 1: pass2 (rows Q)
    const int u    = t & 255;
    const int tr   = u >> 4;             // 0..15
    const int tc   = u & 15;             // 0..15

    const float* Ab = A + (size_t)b * HH * HH;

    // ---- stage raw A tiles: 16 floats (4x float4) per thread, full 64x64 ----
    {
        const int rr = u >> 2;           // 0..63
        const int cs = (u & 3) * 16;     // 0,16,32,48  (covers ALL 64 columns)
        if (half == 0) {
            const float* g = &Ab[(size_t)(p0 + rr) * HH + q0 + cs];
            float* dst = &sLat[rr * LDP + cs];
            #pragma unroll
            for (int q = 0; q < 4; ++q)
                *(float4*)&dst[4 * q] = *(const float4*)&g[4 * q];
        } else if (!diag) {
            const float* g = &Ab[(size_t)(q0 + rr) * HH + p0 + cs];
            float* dst = &sLatT[rr * LDP + cs];
            #pragma unroll
            for (int q = 0; q < 4; ++q)
                *(float4*)&dst[4 * q] = *(const float4*)&g[4 * q];
        }
    }
    // theta tiles, pre-scaled to revolutions
    if (t < TT) {
        float4 v = ((const float4*)theta)[(size_t)b * HH + p0 + t];
        v.x *= C2PI; v.y *= C2PI; v.z *= C2PI; v.w *= C2PI;
        sThP[t] = v;
    } else if (t < 2 * TT) {
        const int w = t - TT;
        float4 v = ((const float4*)theta)[(size_t)b * HH + q0 + w];
        v.x *= C2PI; v.y *= C2PI; v.z *= C2PI; v.w *= C2PI;
        sThQ[w] = v;
    }
    __syncthreads();

    // ---- symmetrize + relu: each (r,c) owned by exactly one thread ----
    // thread t owns r = t>>3, c in [(t&7)*8, (t&7)*8+8)   (512 threads x 8 = 4096)
    {
        const int r  = t >> 3;
        const int c0 = (t & 7) * 8;
        float lv[8];
        if (!diag) {
            #pragma unroll
            for (int e = 0; e < 8; ++e) {
                const int c = c0 + e;
                lv[e] = fmaxf(0.5f * (sLat[r * LDP + c] + sLatT[c * LDP + r]), 0.0f);
            }
            // sLat[r][c] and sLatT[c][r] are read+written ONLY by this thread
            #pragma unroll
            for (int e = 0; e < 8; ++e) {
                const int c = c0 + e;
                sLat [r * LDP + c] = lv[e];
                sLatT[c * LDP + r] = lv[e];
            }
        } else {
            // mirror element owned by another thread: read-all, barrier, write
            #pragma unroll
            for (int e = 0; e < 8; ++e) {
                const int c = c0 + e;
                lv[e] = fmaxf(0.5f * (sLat[r * LDP + c] + sLat[c * LDP + r]), 0.0f);
            }
            __syncthreads();
            #pragma unroll
            for (int e = 0; e < 8; ++e)
                sLat[r * LDP + c0 + e] = lv[e];
        }
    }
    __syncthreads();

    float4* ws4 = (float4*)ws;

    if (half == 0) {
        // rows in P, cols in Q, slot = Q
        do_pass(sLat, sThP, sThQ, alpha, p0, q0, ws4,
                (size_t)(b * NT + Q) * HH + p0, tr, tc);
    } else if (!diag) {
        // rows in Q, cols in P, slot = P
        do_pass(sLatT, sThQ, sThP, alpha, q0, p0, ws4,
                (size_t)(b * NT + P) * HH + q0, tr, tc);
    }
}

__global__ __launch_bounds__(256) void kuramoto_final(
    const float* __restrict__ theta, const float* __restrict__ gamma,
    const float* __restrict__ omega, const float* __restrict__ kappa,
    const float* __restrict__ ws, float* __restrict__ out)
{
    const int idx = blockIdx.x * 256 + threadIdx.x;   // (b,i) flat, 8192 total
    const int i   = idx & (HH - 1);
    const int b   = idx >> 10;
    const float4* w4 = (const float4*)ws;

    float4 psum = w4[((size_t)b * NT) * HH + i];
    #pragma unroll
    for (int o = 1; o < NT; ++o) {
        const float4 q = w4[((size_t)b * NT + o) * HH + i];
        psum.x += q.x; psum.y += q.y; psum.z += q.z; psum.w += q.w;
    }

    const float4 th = ((const float4*)theta)[idx];
    const float4 om = ((const float4*)omega)[i];
    const float4 kp = ((const float4*)kappa)[i];
    const float  g  = gamma[idx];
    const float  inv = 1.0f / HH;   // K_COUP = 1, DT = 1

    float4 o;
    o.x = th.x + om.x + psum.x * inv + kp.x * (g - th.x);
    o.y = th.y + om.y + psum.y * inv + kp.y * (g - th.y);
    o.z = th.z + om.z + psum.z * inv + kp.z * (g - th.z);
    o.w = th.w + om.w + psum.w * inv + kp.w * (g - th.w);
    ((float4*)out)[idx] = o;
}

extern "C" void kernel_launch(void* const* d_in, const int* in_sizes, int n_in,
                              void* d_out, int out_size, void* d_ws, size_t ws_size,
                              hipStream_t stream) {
    const float* theta = (const float*)d_in[0];
    const float* gamma = (const float*)d_in[1];
    const float* A     = (const float*)d_in[2];
    const float* omega = (const float*)d_in[3];
    const float* kappa = (const float*)d_in[4];
    const float* alpha = (const float*)d_in[5];
    float* out = (float*)d_out;
    float* ws  = (float*)d_ws;

    hipLaunchKernelGGL(kuramoto_partial, dim3(BB * NPAIR), dim3(512), 0, stream,
                       theta, A, alpha, ws);
    hipLaunchKernelGGL(kuramoto_final, dim3(BB * HH / 256), dim3(256), 0, stream,
                       theta, gamma, omega, kappa, ws, out);
}

// Round 6
// 93.167 us; speedup vs baseline: 1.1001x; 1.0929x over previous
//
#include <hip/hip_runtime.h>
#include <math.h>

// Problem constants (from reference)
#define BB 8
#define HH 1024
#define DD 4
#define TI 16            // i-rows per block
#define NJC 8            // j-chunks
#define JC (HH / NJC)    // 128 j per block

// ws layout: float4 partial[NJC][BB][HH] = 8*8*1024*16B = 1 MB
//
// Session record (r0-r5): this two-kernel row/col streaming structure is the
// best measured (93.2-95.0us). The timed region is dominated by ~86us of
// harness-unconditional 268MB ws poison fills (2 x ~43us, each HBM-BW-bound;
// proven unconditional in r1 by not using ws at all -> fills remained).
// Restructurings tried and REJECTED on measurement:
//   r1 fused single-kernel (no ws):      kernels ~14us (A read 2x, fewer blocks)
//   r2/r5 symmetric-pair A-read-once:    kernels ~16us — 64x64-tile access
//     (256B segments @4KB stride, scattered across ~1088 blocks) runs HBM at
//     ~2.5-3 TB/s effective; nominal 32MB saving < efficiency loss. This
//     kernel's panel streaming (512B+ segments, col-side 64B reads L2-absorbed
//     because sibling blocks stream the same lines row-side) exceeds 8 TB/s
//     effective on 64MB nominal.

__global__ __launch_bounds__(256, 8) void kuramoto_partial(
    const float* __restrict__ theta, const float* __restrict__ A,
    const float* __restrict__ alpha, float* __restrict__ ws)
{
    const int blk = blockIdx.x;          // ((b*64 + it)*NJC + jc)
    const int jc  = blk & (NJC - 1);
    const int it  = (blk >> 3) & 63;
    const int b   = blk >> 9;
    const int i0  = it * TI;
    const int j0  = jc * JC;
    const int t   = threadIdx.x;
    const int ti  = t >> 4;              // 0..15
    const int tj  = t & 15;              // 0..15

    __shared__ float sTh0[JC], sTh1[JC], sTh2[JC], sTh3[JC];  // SoA theta_j planes (2 KB)
    __shared__ float sAT[JC][TI + 1];                         // A[b, j0+r, i0+c]  (8.7 KB)

    const float* Ab = A + (size_t)b * HH * HH;

    // stage theta_j SoA (threads 0..127, coalesced float4 reads)
    if (t < JC) {
        const float4 v = ((const float4*)theta)[(size_t)b * HH + j0 + t];
        sTh0[t] = v.x; sTh1[t] = v.y; sTh2[t] = v.z; sTh3[t] = v.w;
    }

    // stage transposed A tile: 128 rows x 16 cols, coalesced float4 loads
    {
        const int r = t >> 2;            // 0..63
        const int c = (t & 3) * 4;       // 0,4,8,12
        #pragma unroll
        for (int rr = 0; rr < JC; rr += 64) {
            const int row = rr + r;
            const float4 v = *(const float4*)&Ab[(size_t)(j0 + row) * HH + i0 + c];
            sAT[row][c + 0] = v.x;
            sAT[row][c + 1] = v.y;
            sAT[row][c + 2] = v.z;
            sAT[row][c + 3] = v.w;
        }
    }
    __syncthreads();   // the only barrier

    const float4 thi = ((const float4*)theta)[(size_t)b * HH + i0 + ti];
    const float4* Arow4  = (const float4*)(Ab    + (size_t)(i0 + ti) * HH + j0);
    const float4* alrow4 = (const float4*)(alpha + (size_t)(i0 + ti) * HH + j0);

    float a0 = 0.f, a1 = 0.f, a2 = 0.f, a3 = 0.f;

    #pragma unroll
    for (int s = 0; s < JC / 64; ++s) {          // 2 iters, 4 j's each
        const int q = tj + 16 * s;               // quad index
        const float4 ad = Arow4[q];              // coalesced b128 global
        const float4 al = alrow4[q];             // coalesced b128 global
        const int j = 4 * q;
        #pragma unroll
        for (int k = 0; k < 4; ++k) {
            const float adk = (&ad.x)[k];
            const float alk = (&al.x)[k];
            const float at  = sAT[j + k][ti];    // 2-way bank alias (free)
            const float alat = fmaxf(0.5f * (adk + at), 0.0f);
            a0 += alat * __sinf(sTh0[j + k] - thi.x - alk);
            a1 += alat * __sinf(sTh1[j + k] - thi.y - alk);
            a2 += alat * __sinf(sTh2[j + k] - thi.z - alk);
            a3 += alat * __sinf(sTh3[j + k] - thi.w - alk);
        }
    }

    // reduce over the 16 tj lanes (ti groups are lane-contiguous in a wave)
    #pragma unroll
    for (int off = 8; off >= 1; off >>= 1) {
        a0 += __shfl_down(a0, off, 16);
        a1 += __shfl_down(a1, off, 16);
        a2 += __shfl_down(a2, off, 16);
        a3 += __shfl_down(a3, off, 16);
    }

    if (tj == 0) {
        float4 r; r.x = a0; r.y = a1; r.z = a2; r.w = a3;
        ((float4*)ws)[((size_t)jc * BB + b) * HH + i0 + ti] = r;
    }
}

__global__ __launch_bounds__(256) void kuramoto_final(
    const float* __restrict__ theta, const float* __restrict__ gamma,
    const float* __restrict__ omega, const float* __restrict__ kappa,
    const float* __restrict__ ws, float* __restrict__ out)
{
    const int idx = blockIdx.x * 256 + threadIdx.x;   // (b,i) flat, 8192 total
    const int i   = idx & (HH - 1);
    const float4* w4 = (const float4*)ws;

    float4 p = w4[idx];
    #pragma unroll
    for (int jc = 1; jc < NJC; ++jc) {
        const float4 q = w4[(size_t)jc * BB * HH + idx];
        p.x += q.x; p.y += q.y; p.z += q.z; p.w += q.w;
    }

    const float4 th = ((const float4*)theta)[idx];
    const float4 om = ((const float4*)omega)[i];
    const float4 kp = ((const float4*)kappa)[i];
    const float  g  = gamma[idx];
    const float  inv = 1.0f / HH;   // K_COUP = 1, DT = 1

    float4 o;
    o.x = th.x + om.x + p.x * inv + kp.x * (g - th.x);
    o.y = th.y + om.y + p.y * inv + kp.y * (g - th.y);
    o.z = th.z + om.z + p.z * inv + kp.z * (g - th.z);
    o.w = th.w + om.w + p.w * inv + kp.w * (g - th.w);
    ((float4*)out)[idx] = o;
}

extern "C" void kernel_launch(void* const* d_in, const int* in_sizes, int n_in,
                              void* d_out, int out_size, void* d_ws, size_t ws_size,
                              hipStream_t stream) {
    const float* theta = (const float*)d_in[0];
    const float* gamma = (const float*)d_in[1];
    const float* A     = (const float*)d_in[2];
    const float* omega = (const float*)d_in[3];
    const float* kappa = (const float*)d_in[4];
    const float* alpha = (const float*)d_in[5];
    float* out = (float*)d_out;
    float* ws  = (float*)d_ws;

    hipLaunchKernelGGL(kuramoto_partial, dim3(BB * (HH / TI) * NJC), dim3(256), 0, stream,
                       theta, A, alpha, ws);
    hipLaunchKernelGGL(kuramoto_final, dim3(BB * HH / 256), dim3(256), 0, stream,
                       theta, gamma, omega, kappa, ws, out);
}